// Round 12
// baseline (344.742 us; speedup 1.0000x reference)
//
#include <hip/hip_runtime.h>
#include <hip/hip_cooperative_groups.h>
#include <math.h>

namespace cg = cooperative_groups;

#define BB 8192
#define DD 2048
#define BN_EPS 1e-5f

// ---------------- cooperative fused path (fits the 128-VGPR budget) ----------
#define NBLK 1024
#define NTHR 256
#define RPB  8    // rows per block   (NBLK * RPB == BB)
#define CPT  8    // cols per thread  (NTHR * CPT == DD)
#define NWV  (NTHR / 64)

__global__ __launch_bounds__(NTHR, 4) void k_fused(
    const float* __restrict__ x, const float* __restrict__ w4,
    const float* __restrict__ b4, float* __restrict__ out,
    float* __restrict__ ws)
{
    cg::grid_group grid = cg::this_grid();
    const int t    = threadIdx.x;
    const int blk  = blockIdx.x;
    const int lane = t & 63;
    const int wv   = t >> 6;
    const int row0 = blk * RPB;
    const int c0   = t * CPT;

    float* pscr  = out;          // [NBLK][2][DD] scratch inside d_out (16 MB)
    float* mu_g  = ws;           // [DD]
    float* inv_g = ws + DD;      // [DD]

    __shared__ float lds_red[NWV][RPB];
    __shared__ float lds_s[RPB];
    __shared__ float lds_st[NWV][4];

    float v[RPB][CPT];
    {
        const float* xp = x + (size_t)row0 * DD + c0;
        #pragma unroll
        for (int r = 0; r < RPB; ++r) {
            *(float4*)&v[r][0] = *(const float4*)xp;
            *(float4*)&v[r][4] = *(const float4*)(xp + 4);
            xp += DD;
        }
    }

    for (int l = 0; l < 4; ++l) {
        {
            float wr[CPT];
            *(float4*)&wr[0] = *(const float4*)(w4 + l * DD + c0);
            *(float4*)&wr[4] = *(const float4*)(w4 + l * DD + c0 + 4);
            float p[RPB];
            #pragma unroll
            for (int r = 0; r < RPB; ++r) {
                float a = v[r][0] * wr[0];
                #pragma unroll
                for (int j = 1; j < CPT; ++j) a = fmaf(v[r][j], wr[j], a);
                p[r] = a;
            }
            #pragma unroll
            for (int off = 32; off; off >>= 1) {
                #pragma unroll
                for (int r = 0; r < RPB; ++r)
                    p[r] += __shfl_xor(p[r], off, 64);
            }
            if (lane == 0) {
                #pragma unroll
                for (int r = 0; r < RPB; ++r) lds_red[wv][r] = p[r];
            }
        }
        __syncthreads();
        if (t < RPB) {
            float a = 0.f;
            #pragma unroll
            for (int w = 0; w < NWV; ++w) a += lds_red[w][t];
            lds_s[t] = a;
        }
        __syncthreads();

        {
            float bv[CPT];
            *(float4*)&bv[0] = *(const float4*)(b4 + l * DD + c0);
            *(float4*)&bv[4] = *(const float4*)(b4 + l * DD + c0 + 4);
            const float* xp = x + (size_t)row0 * DD + c0;
            #pragma unroll
            for (int r = 0; r < RPB; ++r) {
                float xv[CPT];
                *(float4*)&xv[0] = *(const float4*)xp;
                *(float4*)&xv[4] = *(const float4*)(xp + 4);
                xp += DD;
                const float sv = lds_s[r];
                #pragma unroll
                for (int j = 0; j < CPT; ++j)
                    v[r][j] = fmaf(xv[j], sv, bv[j] + v[r][j]);
            }
        }

        {
            float cs[CPT], cq[CPT];
            #pragma unroll
            for (int j = 0; j < CPT; ++j) { cs[j] = 0.f; cq[j] = 0.f; }
            #pragma unroll
            for (int r = 0; r < RPB; ++r) {
                #pragma unroll
                for (int j = 0; j < CPT; ++j) {
                    cs[j] += v[r][j];
                    cq[j]  = fmaf(v[r][j], v[r][j], cq[j]);
                }
            }
            float* pp = pscr + (size_t)blk * 2 * DD;
            *(float4*)(pp + c0)          = *(float4*)&cs[0];
            *(float4*)(pp + c0 + 4)      = *(float4*)&cs[4];
            *(float4*)(pp + DD + c0)     = *(float4*)&cq[0];
            *(float4*)(pp + DD + c0 + 4) = *(float4*)&cq[4];
        }

        grid.sync();

        {
            const int cb = blk * 2;
            float a0 = 0.f, a1 = 0.f, q0 = 0.f, q1 = 0.f;
            #pragma unroll
            for (int k = 0; k < NBLK / NTHR; ++k) {
                const float* pb = pscr + (size_t)(t + k * NTHR) * 2 * DD;
                a0 += pb[cb];      a1 += pb[cb + 1];
                q0 += pb[DD + cb]; q1 += pb[DD + cb + 1];
            }
            #pragma unroll
            for (int off = 32; off; off >>= 1) {
                a0 += __shfl_xor(a0, off, 64);
                a1 += __shfl_xor(a1, off, 64);
                q0 += __shfl_xor(q0, off, 64);
                q1 += __shfl_xor(q1, off, 64);
            }
            if (lane == 0) {
                lds_st[wv][0] = a0; lds_st[wv][1] = q0;
                lds_st[wv][2] = a1; lds_st[wv][3] = q1;
            }
            __syncthreads();
            if (t == 0) {
                float A0 = lds_st[0][0] + lds_st[1][0] + lds_st[2][0] + lds_st[3][0];
                float Q0 = lds_st[0][1] + lds_st[1][1] + lds_st[2][1] + lds_st[3][1];
                float A1 = lds_st[0][2] + lds_st[1][2] + lds_st[2][2] + lds_st[3][2];
                float Q1 = lds_st[0][3] + lds_st[1][3] + lds_st[2][3] + lds_st[3][3];
                const float m0 = A0 / (float)BB, m1 = A1 / (float)BB;
                mu_g[cb]      = m0;
                mu_g[cb + 1]  = m1;
                inv_g[cb]     = rsqrtf(fmaxf(Q0 / (float)BB - m0 * m0, 0.f) + BN_EPS);
                inv_g[cb + 1] = rsqrtf(fmaxf(Q1 / (float)BB - m1 * m1, 0.f) + BN_EPS);
            }
        }

        grid.sync();

        {
            float mv[CPT], iv[CPT];
            *(float4*)&mv[0] = *(const float4*)(mu_g + c0);
            *(float4*)&mv[4] = *(const float4*)(mu_g + c0 + 4);
            *(float4*)&iv[0] = *(const float4*)(inv_g + c0);
            *(float4*)&iv[4] = *(const float4*)(inv_g + c0 + 4);
            #pragma unroll
            for (int r = 0; r < RPB; ++r) {
                #pragma unroll
                for (int j = 0; j < CPT; ++j)
                    v[r][j] = (v[r][j] - mv[j]) * iv[j];
            }
        }
    }

    {
        float* op = out + (size_t)row0 * DD + c0;
        #pragma unroll
        for (int r = 0; r < RPB; ++r) {
            *(float4*)op       = *(float4*)&v[r][0];
            *(float4*)(op + 4) = *(float4*)&v[r][4];
            op += DD;
        }
    }
}

// ---- gate-diagnosis markers (profile-visible; write only into ws) ----------
__global__ void k_gate_spill(float* ws, int v) { if (threadIdx.x == 0) ws[0] = (float)v; }
__global__ void k_gate_occ(float* ws, int v)   { if (threadIdx.x == 0) ws[1] = (float)v; }

// ---------------- optimized fallback: high-occupancy per-layer kernel --------
// nb blocks of (BB/nb) rows, 256 thr. At nb=2048 (4 rows): 8 blocks/CU @ 52
// VGPR -> 32 waves/CU (r11 measured 29% occ at nb=1024 -> latency-bound).
__global__ __launch_bounds__(256) void k_layer2(
    const float* __restrict__ x, const float* __restrict__ raw,
    const float* __restrict__ w, const float* __restrict__ bias,
    const float* __restrict__ mu, const float* __restrict__ inv,
    float* __restrict__ outbuf, float* __restrict__ partials,
    int rows, int use_norm)
{
    const int t    = threadIdx.x;
    const int lane = t & 63;
    const int wv   = t >> 6;
    const int blk  = blockIdx.x;
    const int row0 = blk * rows;

    __shared__ float lds_s[32];

    for (int rr = wv; rr < rows; rr += 4) {
        const float* rp = raw + (size_t)(row0 + rr) * DD;
        float acc = 0.f;
        #pragma unroll
        for (int k = 0; k < DD / 256; ++k) {
            const int idx = k * 256 + lane * 4;
            float4 rv  = *(const float4*)(rp + idx);
            const float4 wv4 = *(const float4*)(w + idx);
            if (use_norm) {
                const float4 m  = *(const float4*)(mu + idx);
                const float4 iv = *(const float4*)(inv + idx);
                rv.x = (rv.x - m.x) * iv.x;
                rv.y = (rv.y - m.y) * iv.y;
                rv.z = (rv.z - m.z) * iv.z;
                rv.w = (rv.w - m.w) * iv.w;
            }
            acc += rv.x * wv4.x + rv.y * wv4.y + rv.z * wv4.z + rv.w * wv4.w;
        }
        #pragma unroll
        for (int off = 32; off; off >>= 1) acc += __shfl_xor(acc, off, 64);
        if (lane == 0) lds_s[rr] = acc;
    }
    __syncthreads();

    const int c0 = t * 8;
    float bv[8], mv[8], iv8[8];
    *(float4*)&bv[0] = *(const float4*)(bias + c0);
    *(float4*)&bv[4] = *(const float4*)(bias + c0 + 4);
    if (use_norm) {
        *(float4*)&mv[0]  = *(const float4*)(mu + c0);
        *(float4*)&mv[4]  = *(const float4*)(mu + c0 + 4);
        *(float4*)&iv8[0] = *(const float4*)(inv + c0);
        *(float4*)&iv8[4] = *(const float4*)(inv + c0 + 4);
    } else {
        #pragma unroll
        for (int j = 0; j < 8; ++j) { mv[j] = 0.f; iv8[j] = 1.f; }
    }
    float cs[8], cq[8];
    #pragma unroll
    for (int j = 0; j < 8; ++j) { cs[j] = 0.f; cq[j] = 0.f; }

    const float* rp = raw + (size_t)row0 * DD + c0;
    const float* xp = x   + (size_t)row0 * DD + c0;
    float*       op = outbuf + (size_t)row0 * DD + c0;
    for (int r = 0; r < rows; ++r) {
        float rv[8], xv[8];
        *(float4*)&rv[0] = *(const float4*)rp;
        *(float4*)&rv[4] = *(const float4*)(rp + 4);
        *(float4*)&xv[0] = *(const float4*)xp;
        *(float4*)&xv[4] = *(const float4*)(xp + 4);
        const float sv = lds_s[r];
        float o[8];
        #pragma unroll
        for (int j = 0; j < 8; ++j) {
            o[j] = fmaf(xv[j], sv, bv[j] + (rv[j] - mv[j]) * iv8[j]);
            cs[j] += o[j];
            cq[j]  = fmaf(o[j], o[j], cq[j]);
        }
        *(float4*)op       = *(float4*)&o[0];
        *(float4*)(op + 4) = *(float4*)&o[4];
        rp += DD; xp += DD; op += DD;
    }
    float* pp = partials + (size_t)blk * 2 * DD;
    *(float4*)(pp + c0)          = *(float4*)&cs[0];
    *(float4*)(pp + c0 + 4)      = *(float4*)&cs[4];
    *(float4*)(pp + DD + c0)     = *(float4*)&cq[0];
    *(float4*)(pp + DD + c0 + 4) = *(float4*)&cq[4];
}

__global__ __launch_bounds__(256) void k_stats_a(
    const float* __restrict__ partials, float* __restrict__ mid, int nb_per_pg)
{
    const int pg = blockIdx.x >> 4;
    const int ec = blockIdx.x & 15;
    const int e  = ec * 256 + threadIdx.x;
    const int p0 = pg * nb_per_pg;
    float acc = 0.f;
    for (int p = 0; p < nb_per_pg; ++p)
        acc += partials[(size_t)(p0 + p) * (2 * DD) + e];
    mid[(size_t)pg * (2 * DD) + e] = acc;
}

__global__ __launch_bounds__(256) void k_stats_b(
    const float* __restrict__ mid, float* __restrict__ mu, float* __restrict__ inv)
{
    const int col = blockIdx.x * 256 + threadIdx.x;
    float sum = 0.f, sq = 0.f;
    #pragma unroll
    for (int p = 0; p < 16; ++p) {
        sum += mid[(size_t)p * 2 * DD + col];
        sq  += mid[(size_t)p * 2 * DD + DD + col];
    }
    const float m = sum / (float)BB;
    const float var = fmaxf(sq / (float)BB - m * m, 0.f);
    mu[col]  = m;
    inv[col] = rsqrtf(var + BN_EPS);
}

__global__ __launch_bounds__(256) void k_norm(
    float* __restrict__ out, const float* __restrict__ mu, const float* __restrict__ inv)
{
    const size_t i = ((size_t)blockIdx.x * 256 + threadIdx.x) * 4;
    const int c = (int)(i & (DD - 1));
    float4 v = *(float4*)(out + i);
    const float4 m  = *(const float4*)(mu + c);
    const float4 iv = *(const float4*)(inv + c);
    v.x = (v.x - m.x) * iv.x;
    v.y = (v.y - m.y) * iv.y;
    v.z = (v.z - m.z) * iv.z;
    v.w = (v.w - m.w) * iv.w;
    *(float4*)(out + i) = v;
}

extern "C" void kernel_launch(void* const* d_in, const int* in_sizes, int n_in,
                              void* d_out, int out_size, void* d_ws, size_t ws_size,
                              hipStream_t stream) {
    const float* x  = (const float*)d_in[0];   // [B, D]
    const float* w  = (const float*)d_in[1];   // [4, D]
    const float* bb = (const float*)d_in[2];   // [4, D]
    float* out = (float*)d_out;
    float* ws  = (float*)d_ws;

    // ---- coop path gates: no spill + >=4 blocks/CU (1024 blocks / 256 CUs)
    bool coop_ok = false;
    if (ws_size >= 2 * DD * sizeof(float)) {
        hipFuncAttributes fa;
        hipError_t ae = hipFuncGetAttributes(&fa, (const void*)k_fused);
        int blocks_per_cu = 0;
        hipError_t qe = hipOccupancyMaxActiveBlocksPerMultiprocessor(
            &blocks_per_cu, (const void*)k_fused, NTHR, 0);
        if (ae == hipSuccess && qe == hipSuccess) {
            if (fa.localSizeBytes != 0)
                k_gate_spill<<<1, 64, 0, stream>>>(ws, (int)fa.localSizeBytes);
            if (blocks_per_cu < 4)
                k_gate_occ<<<1, 64, 0, stream>>>(ws, blocks_per_cu);
            if (fa.localSizeBytes == 0 && blocks_per_cu >= 4) {
                void* args[] = { (void*)&x, (void*)&w, (void*)&bb, (void*)&out, (void*)&ws };
                hipError_t e = hipLaunchCooperativeKernel((const void*)k_fused, dim3(NBLK),
                                                          dim3(NTHR), args, 0, stream);
                coop_ok = (e == hipSuccess);
            }
        }
    }
    if (coop_ok) return;

    // ---- fallback: optimized multi-kernel path
    // ws layout (floats): mu[DD] | inv[DD] | mid[16*2*DD] | partials[nb*2*DD]
    float* mu_buf   = ws;
    float* inv_buf  = mu_buf + DD;
    float* mid_buf  = inv_buf + DD;
    float* partials = mid_buf + 16 * 2 * DD;
    const size_t base_bytes = (size_t)(partials - ws) * sizeof(float);

    int nb = 2048;
    while (nb > 256 && base_bytes + (size_t)nb * 2 * DD * sizeof(float) > ws_size)
        nb >>= 1;
    const int rows = BB / nb;

    for (int l = 0; l < 4; ++l) {
        const float* raw = (l == 0) ? x : out;
        k_layer2<<<nb, 256, 0, stream>>>(x, raw, w + l * DD, bb + l * DD,
                                         mu_buf, inv_buf, out, partials, rows, l != 0);
        k_stats_a<<<256, 256, 0, stream>>>(partials, mid_buf, nb / 16);
        k_stats_b<<<DD / 256, 256, 0, stream>>>(mid_buf, mu_buf, inv_buf);
    }
    k_norm<<<(BB * DD / 4) / 256, 256, 0, stream>>>(out, mu_buf, inv_buf);
}

// Round 13
// 281.891 us; speedup vs baseline: 1.2230x; 1.2230x over previous
//
#include <hip/hip_runtime.h>
#include <math.h>

#define BB 8192
#define DD 2048
#define BN_EPS 1e-5f
#define NB 512          // pass blocks
#define RPB 16          // rows per pass block
#define PASS_THR 512

// ws layout (floats)
#define OFF_T  0                    // tbuf[4][BB]   (t_k = s_{k-1})
#define OFF_A  (4 * BB)             // a[DD]
#define OFF_C  (OFF_A + DD)         // c[4][DD]
#define OFF_E  (OFF_C + 4 * DD)     // e[DD]
#define OFF_M1 (OFF_E + DD)         // M1[5][DD]   M1_k = sum_b x * t_k   (t_0 = 1)
#define OFF_M2 (OFF_M1 + 5 * DD)    // M2[15][DD]  M2_{jk} = sum_b x^2 t_j t_k, j<=k
#define OFF_MN (OFF_M2 + 15 * DD)   // Mnew[6][DD]
#define OFF_P  (OFF_MN + 6 * DD)    // partials[NB][nv][DD]

__host__ __device__ constexpr int P2(int j, int k) { return k * (k + 1) / 2 + j; }

// One pass over x per layer: per row compute s (z-dots + row combo), store t,
// and accumulate the layer's NEW column moments as per-block partials.
template <int LAY>
__global__ __launch_bounds__(PASS_THR) void k_pass(
    const float* __restrict__ x, const float* __restrict__ w4, float* __restrict__ ws)
{
    constexpr int NV = (LAY == 0) ? 5 : (3 + LAY);
    const float* avec = ws + OFF_A;
    const float* cvec = ws + OFF_C;
    const float* evec = ws + OFF_E;
    float* tbuf     = ws + OFF_T;
    float* partials = ws + OFF_P;

    const int t    = threadIdx.x;
    const int lane = t & 63;
    const int wv   = t >> 6;            // 8 waves
    const int blk  = blockIdx.x;
    const int row0 = blk * RPB;
    const int c0   = t * 4;
    const float* wl = w4 + LAY * DD;

    __shared__ float lds_z[8][4][4];    // [wave][rowInGroup][zIdx]
    __shared__ float lds_s[4];
    __shared__ float lds_tv[4][4];      // [rowInGroup][j-1]
    __shared__ float lds_dote[8];

    float wr[4];
    *(float4*)&wr[0] = *(const float4*)(wl + c0);

    // u_j slices for this thread's 4 columns
    float u0[4], u1[4], u2[4], u3[4];
    if constexpr (LAY == 0) {
        #pragma unroll
        for (int i = 0; i < 4; ++i) u0[i] = wr[i];
    } else {
        float a4[4]; *(float4*)&a4[0] = *(const float4*)(avec + c0);
        #pragma unroll
        for (int i = 0; i < 4; ++i) u0[i] = a4[i] * wr[i];
    }
    if constexpr (LAY >= 1) {
        float cc[4]; *(float4*)&cc[0] = *(const float4*)(cvec + 0 * DD + c0);
        #pragma unroll
        for (int i = 0; i < 4; ++i) u1[i] = cc[i] * wr[i];
    }
    if constexpr (LAY >= 2) {
        float cc[4]; *(float4*)&cc[0] = *(const float4*)(cvec + 1 * DD + c0);
        #pragma unroll
        for (int i = 0; i < 4; ++i) u2[i] = cc[i] * wr[i];
    }
    if constexpr (LAY >= 3) {
        float cc[4]; *(float4*)&cc[0] = *(const float4*)(cvec + 2 * DD + c0);
        #pragma unroll
        for (int i = 0; i < 4; ++i) u3[i] = cc[i] * wr[i];
    }

    float dote = 0.f;
    if constexpr (LAY > 0) {
        float e4[4]; *(float4*)&e4[0] = *(const float4*)(evec + c0);
        float p = e4[0] * wr[0] + e4[1] * wr[1] + e4[2] * wr[2] + e4[3] * wr[3];
        #pragma unroll
        for (int off = 32; off; off >>= 1) p += __shfl_xor(p, off, 64);
        if (lane == 0) lds_dote[wv] = p;
        __syncthreads();
        dote = lds_dote[0] + lds_dote[1] + lds_dote[2] + lds_dote[3]
             + lds_dote[4] + lds_dote[5] + lds_dote[6] + lds_dote[7];
    }

    // moment partial accumulators (this thread's 4 columns)
    float pa_m1[4] = {0, 0, 0, 0};   // sum x*s
    float pa_20[4] = {0, 0, 0, 0};   // sum x^2*s
    float pa_j1[4] = {0, 0, 0, 0};   // sum x^2*s*t_1
    float pa_j2[4] = {0, 0, 0, 0};
    float pa_j3[4] = {0, 0, 0, 0};
    float pa_nn[4] = {0, 0, 0, 0};   // sum x^2*s^2
    float pa_X1[4] = {0, 0, 0, 0};   // sum x       (LAY==0)
    float pa_X2[4] = {0, 0, 0, 0};   // sum x^2     (LAY==0)

    #pragma unroll
    for (int g = 0; g < RPB / 4; ++g) {
        float xr[4][4];
        float zp[4][4];
        #pragma unroll
        for (int rr = 0; rr < 4; ++rr) {
            const int row = row0 + g * 4 + rr;
            *(float4*)&xr[rr][0] = *(const float4*)(x + (size_t)row * DD + c0);
            zp[rr][0] = xr[rr][0] * u0[0] + xr[rr][1] * u0[1]
                      + xr[rr][2] * u0[2] + xr[rr][3] * u0[3];
            if constexpr (LAY >= 1)
                zp[rr][1] = xr[rr][0] * u1[0] + xr[rr][1] * u1[1]
                          + xr[rr][2] * u1[2] + xr[rr][3] * u1[3];
            if constexpr (LAY >= 2)
                zp[rr][2] = xr[rr][0] * u2[0] + xr[rr][1] * u2[1]
                          + xr[rr][2] * u2[2] + xr[rr][3] * u2[3];
            if constexpr (LAY >= 3)
                zp[rr][3] = xr[rr][0] * u3[0] + xr[rr][1] * u3[1]
                          + xr[rr][2] * u3[2] + xr[rr][3] * u3[3];
        }
        #pragma unroll
        for (int off = 32; off; off >>= 1) {
            #pragma unroll
            for (int rr = 0; rr < 4; ++rr) {
                zp[rr][0] += __shfl_xor(zp[rr][0], off, 64);
                if constexpr (LAY >= 1) zp[rr][1] += __shfl_xor(zp[rr][1], off, 64);
                if constexpr (LAY >= 2) zp[rr][2] += __shfl_xor(zp[rr][2], off, 64);
                if constexpr (LAY >= 3) zp[rr][3] += __shfl_xor(zp[rr][3], off, 64);
            }
        }
        if (lane == 0) {
            #pragma unroll
            for (int rr = 0; rr < 4; ++rr) {
                lds_z[wv][rr][0] = zp[rr][0];
                if constexpr (LAY >= 1) lds_z[wv][rr][1] = zp[rr][1];
                if constexpr (LAY >= 2) lds_z[wv][rr][2] = zp[rr][2];
                if constexpr (LAY >= 3) lds_z[wv][rr][3] = zp[rr][3];
            }
        }
        __syncthreads();
        if (t < 4) {
            const int row = row0 + g * 4 + t;
            float z[4] = {0, 0, 0, 0};
            #pragma unroll
            for (int w = 0; w < 8; ++w) {
                z[0] += lds_z[w][t][0];
                if constexpr (LAY >= 1) z[1] += lds_z[w][t][1];
                if constexpr (LAY >= 2) z[2] += lds_z[w][t][2];
                if constexpr (LAY >= 3) z[3] += lds_z[w][t][3];
            }
            float s = z[0] + dote;
            if constexpr (LAY >= 1) {
                const float tv = tbuf[0 * BB + row];
                lds_tv[t][0] = tv; s += tv * z[1];
            }
            if constexpr (LAY >= 2) {
                const float tv = tbuf[1 * BB + row];
                lds_tv[t][1] = tv; s += tv * z[2];
            }
            if constexpr (LAY >= 3) {
                const float tv = tbuf[2 * BB + row];
                lds_tv[t][2] = tv; s += tv * z[3];
            }
            tbuf[LAY * BB + row] = s;
            lds_s[t] = s;
        }
        __syncthreads();
        #pragma unroll
        for (int rr = 0; rr < 4; ++rr) {
            const float s = lds_s[rr];
            #pragma unroll
            for (int i = 0; i < 4; ++i) {
                const float xa = xr[rr][i];
                const float x2 = xa * xa;
                pa_m1[i] = fmaf(xa, s, pa_m1[i]);
                pa_20[i] = fmaf(x2, s, pa_20[i]);
                if constexpr (LAY >= 1) pa_j1[i] = fmaf(x2 * s, lds_tv[rr][0], pa_j1[i]);
                if constexpr (LAY >= 2) pa_j2[i] = fmaf(x2 * s, lds_tv[rr][1], pa_j2[i]);
                if constexpr (LAY >= 3) pa_j3[i] = fmaf(x2 * s, lds_tv[rr][2], pa_j3[i]);
                pa_nn[i] = fmaf(x2 * s, s, pa_nn[i]);
                if constexpr (LAY == 0) {
                    pa_X1[i] += xa;
                    pa_X2[i] += x2;
                }
            }
        }
    }

    // store partials: v ordering must match k_stats/k_reduce
    float* pp = partials + (size_t)blk * NV * DD + c0;
    *(float4*)(pp + 0 * DD) = *(float4*)&pa_m1[0];
    *(float4*)(pp + 1 * DD) = *(float4*)&pa_20[0];
    if constexpr (LAY == 0) {
        *(float4*)(pp + 2 * DD) = *(float4*)&pa_nn[0];
        *(float4*)(pp + 3 * DD) = *(float4*)&pa_X1[0];
        *(float4*)(pp + 4 * DD) = *(float4*)&pa_X2[0];
    } else {
        if constexpr (LAY >= 1) *(float4*)(pp + 2 * DD) = *(float4*)&pa_j1[0];
        if constexpr (LAY >= 2) *(float4*)(pp + 3 * DD) = *(float4*)&pa_j2[0];
        if constexpr (LAY >= 3) *(float4*)(pp + 4 * DD) = *(float4*)&pa_j3[0];
        *(float4*)(pp + (2 + LAY) * DD) = *(float4*)&pa_nn[0];
    }
}

__global__ __launch_bounds__(256) void k_reduce(float* __restrict__ ws, int nv)
{
    const int v   = blockIdx.x >> 3;
    const int col = (blockIdx.x & 7) * 256 + threadIdx.x;
    const float* partials = ws + OFF_P;
    float acc = 0.f;
    for (int p = 0; p < NB; ++p)
        acc += partials[((size_t)p * nv + v) * DD + col];
    ws[OFF_MN + (size_t)v * DD + col] = acc;
}

template <int LAY>
__global__ __launch_bounds__(256) void k_stats(float* __restrict__ ws,
                                               const float* __restrict__ b4)
{
    const int d = blockIdx.x * 256 + threadIdx.x;
    constexpr int L = LAY + 1;
    float* M1 = ws + OFF_M1;
    float* M2 = ws + OFF_M2;
    const float* Mn = ws + OFF_MN;
    float* a = ws + OFF_A;
    float* c = ws + OFF_C;
    float* e = ws + OFF_E;
    const float invB = 1.f / (float)BB;

    float g[5], m1v[5], m2v[5][5];

    g[0] = (LAY == 0) ? 1.f : a[d];
    #pragma unroll
    for (int k = 1; k <= LAY; ++k) g[k] = c[(k - 1) * DD + d];
    g[L] = 1.f;

    if constexpr (LAY == 0) m1v[0] = Mn[3 * DD + d];
    else                    m1v[0] = M1[0 * DD + d];
    #pragma unroll
    for (int k = 1; k <= LAY; ++k) m1v[k] = M1[k * DD + d];
    m1v[L] = Mn[0 * DD + d];

    if constexpr (LAY == 0) {
        m2v[0][0] = Mn[4 * DD + d];
    } else {
        #pragma unroll
        for (int k = 0; k <= LAY; ++k)
            #pragma unroll
            for (int j = 0; j <= LAY; ++j)
                if (j <= k) m2v[j][k] = M2[P2(j, k) * DD + d];
    }
    m2v[0][L] = Mn[1 * DD + d];
    #pragma unroll
    for (int j = 1; j <= LAY; ++j) m2v[j][L] = Mn[(1 + j) * DD + d];
    m2v[L][L] = Mn[(2 + LAY) * DD + d];

    // persist new moments
    M1[L * DD + d]         = m1v[L];
    M2[P2(0, L) * DD + d]  = m2v[0][L];
    #pragma unroll
    for (int j = 1; j <= LAY; ++j) M2[P2(j, L) * DD + d] = m2v[j][L];
    M2[P2(L, L) * DD + d]  = m2v[L][L];
    if constexpr (LAY == 0) { M1[0 * DD + d] = m1v[0]; M2[0 * DD + d] = m2v[0][0]; }

    // stats
    const float E = ((LAY == 0) ? 0.f : e[d]) + b4[LAY * DD + d];
    float mxG = 0.f;
    #pragma unroll
    for (int k = 0; k <= L; ++k) mxG += g[k] * m1v[k];
    mxG *= invB;
    const float mu = mxG + E;
    float ex2 = 0.f;
    #pragma unroll
    for (int k = 0; k <= L; ++k) {
        ex2 += g[k] * g[k] * m2v[k][k];
        #pragma unroll
        for (int j = 0; j <= L; ++j)
            if (j < k) ex2 += 2.f * g[j] * g[k] * m2v[j][k];
    }
    ex2 *= invB;
    const float second = ex2 + 2.f * E * mxG + E * E;
    const float var = fmaxf(second - mu * mu, 0.f);
    const float inv = rsqrtf(var + BN_EPS);

    a[d] = g[0] * inv;
    #pragma unroll
    for (int k = 1; k <= LAY; ++k) c[(k - 1) * DD + d] = g[k] * inv;
    c[(L - 1) * DD + d] = inv;
    e[d] = (E - mu) * inv;
}

// out[b,d] = x[b,d]*(a[d] + sum_k c_k[d]*t_k[b]) + e[d]
__global__ __launch_bounds__(256) void k_final(
    const float* __restrict__ x, const float* __restrict__ ws, float* __restrict__ out)
{
    const int t = threadIdx.x;
    const int blk = blockIdx.x;
    const int row0 = blk * 8;
    const int c0 = t * 8;
    const float* a = ws + OFF_A;
    const float* c = ws + OFF_C;
    const float* e = ws + OFF_E;
    const float* tbuf = ws + OFF_T;

    __shared__ float lt[4][8];
    if (t < 32) lt[t >> 3][t & 7] = tbuf[(t >> 3) * BB + row0 + (t & 7)];
    __syncthreads();

    float a8[8], e8[8], c8[4][8];
    *(float4*)&a8[0] = *(const float4*)(a + c0);
    *(float4*)&a8[4] = *(const float4*)(a + c0 + 4);
    *(float4*)&e8[0] = *(const float4*)(e + c0);
    *(float4*)&e8[4] = *(const float4*)(e + c0 + 4);
    #pragma unroll
    for (int k = 0; k < 4; ++k) {
        *(float4*)&c8[k][0] = *(const float4*)(c + k * DD + c0);
        *(float4*)&c8[k][4] = *(const float4*)(c + k * DD + c0 + 4);
    }
    #pragma unroll
    for (int r = 0; r < 8; ++r) {
        const size_t base = (size_t)(row0 + r) * DD + c0;
        float xv[8], o[8];
        *(float4*)&xv[0] = *(const float4*)(x + base);
        *(float4*)&xv[4] = *(const float4*)(x + base + 4);
        const float t0 = lt[0][r], t1 = lt[1][r], t2 = lt[2][r], t3 = lt[3][r];
        #pragma unroll
        for (int i = 0; i < 8; ++i) {
            float gg = a8[i];
            gg = fmaf(c8[0][i], t0, gg);
            gg = fmaf(c8[1][i], t1, gg);
            gg = fmaf(c8[2][i], t2, gg);
            gg = fmaf(c8[3][i], t3, gg);
            o[i] = fmaf(xv[i], gg, e8[i]);
        }
        *(float4*)(out + base)     = *(float4*)&o[0];
        *(float4*)(out + base + 4) = *(float4*)&o[4];
    }
}

extern "C" void kernel_launch(void* const* d_in, const int* in_sizes, int n_in,
                              void* d_out, int out_size, void* d_ws, size_t ws_size,
                              hipStream_t stream) {
    const float* x  = (const float*)d_in[0];   // [B, D]
    const float* w  = (const float*)d_in[1];   // [4, D]
    const float* bb = (const float*)d_in[2];   // [4, D]
    float* out = (float*)d_out;
    float* ws  = (float*)d_ws;

    k_pass<0><<<NB, PASS_THR, 0, stream>>>(x, w, ws);
    k_reduce<<<5 * 8, 256, 0, stream>>>(ws, 5);
    k_stats<0><<<8, 256, 0, stream>>>(ws, bb);

    k_pass<1><<<NB, PASS_THR, 0, stream>>>(x, w, ws);
    k_reduce<<<4 * 8, 256, 0, stream>>>(ws, 4);
    k_stats<1><<<8, 256, 0, stream>>>(ws, bb);

    k_pass<2><<<NB, PASS_THR, 0, stream>>>(x, w, ws);
    k_reduce<<<5 * 8, 256, 0, stream>>>(ws, 5);
    k_stats<2><<<8, 256, 0, stream>>>(ws, bb);

    k_pass<3><<<NB, PASS_THR, 0, stream>>>(x, w, ws);
    k_reduce<<<6 * 8, 256, 0, stream>>>(ws, 6);
    k_stats<3><<<8, 256, 0, stream>>>(ws, bb);

    k_final<<<BB / 8, 256, 0, stream>>>(x, ws, out);
}

// Round 15
// 154.046 us; speedup vs baseline: 2.2379x; 1.8299x over previous
//
#include <hip/hip_runtime.h>
#include <math.h>

#define BB 8192
#define DD 2048
#define BN_EPS 1e-5f
#define NB 512          // pass blocks
#define RPB 16          // rows per pass block
#define PASS_THR 512

// ws layout (floats)
#define OFF_T  0                    // tbuf[4][BB]   (t_k = s_{k-1})
#define OFF_A  (4 * BB)             // a[DD]
#define OFF_C  (OFF_A + DD)         // c[4][DD]
#define OFF_E  (OFF_C + 4 * DD)     // e[DD]
#define OFF_M1 (OFF_E + DD)         // M1[5][DD]   M1_k = sum_b x * t_k   (t_0 = 1)
#define OFF_M2 (OFF_M1 + 5 * DD)    // M2[15][DD]  M2_{jk} = sum_b x^2 t_j t_k, j<=k
#define OFF_MID (OFF_M2 + 15 * DD)  // mid[16][6][DD]  stage-A reduced partials
#define OFF_P  (OFF_MID + 16 * 6 * DD) // partials[NB][nv][DD]

__host__ __device__ constexpr int P2(int j, int k) { return k * (k + 1) / 2 + j; }

// One pass over x per layer: per row compute s (z-dots + row combo), store t,
// and accumulate the layer's NEW column moments as per-block partials.
template <int LAY>
__global__ __launch_bounds__(PASS_THR) void k_pass(
    const float* __restrict__ x, const float* __restrict__ w4, float* __restrict__ ws)
{
    constexpr int NV = (LAY == 0) ? 5 : (3 + LAY);
    const float* avec = ws + OFF_A;
    const float* cvec = ws + OFF_C;
    const float* evec = ws + OFF_E;
    float* tbuf     = ws + OFF_T;
    float* partials = ws + OFF_P;

    const int t    = threadIdx.x;
    const int lane = t & 63;
    const int wv   = t >> 6;            // 8 waves
    const int blk  = blockIdx.x;
    const int row0 = blk * RPB;
    const int c0   = t * 4;
    const float* wl = w4 + LAY * DD;

    __shared__ float lds_z[8][4][4];    // [wave][rowInGroup][zIdx]
    __shared__ float lds_s[4];
    __shared__ float lds_tv[4][4];      // [rowInGroup][j-1]
    __shared__ float lds_dote[8];

    float wr[4];
    *(float4*)&wr[0] = *(const float4*)(wl + c0);

    // u_j slices for this thread's 4 columns
    float u0[4], u1[4], u2[4], u3[4];
    if constexpr (LAY == 0) {
        #pragma unroll
        for (int i = 0; i < 4; ++i) u0[i] = wr[i];
    } else {
        float a4[4]; *(float4*)&a4[0] = *(const float4*)(avec + c0);
        #pragma unroll
        for (int i = 0; i < 4; ++i) u0[i] = a4[i] * wr[i];
    }
    if constexpr (LAY >= 1) {
        float cc[4]; *(float4*)&cc[0] = *(const float4*)(cvec + 0 * DD + c0);
        #pragma unroll
        for (int i = 0; i < 4; ++i) u1[i] = cc[i] * wr[i];
    }
    if constexpr (LAY >= 2) {
        float cc[4]; *(float4*)&cc[0] = *(const float4*)(cvec + 1 * DD + c0);
        #pragma unroll
        for (int i = 0; i < 4; ++i) u2[i] = cc[i] * wr[i];
    }
    if constexpr (LAY >= 3) {
        float cc[4]; *(float4*)&cc[0] = *(const float4*)(cvec + 2 * DD + c0);
        #pragma unroll
        for (int i = 0; i < 4; ++i) u3[i] = cc[i] * wr[i];
    }

    float dote = 0.f;
    if constexpr (LAY > 0) {
        float e4[4]; *(float4*)&e4[0] = *(const float4*)(evec + c0);
        float p = e4[0] * wr[0] + e4[1] * wr[1] + e4[2] * wr[2] + e4[3] * wr[3];
        #pragma unroll
        for (int off = 32; off; off >>= 1) p += __shfl_xor(p, off, 64);
        if (lane == 0) lds_dote[wv] = p;
        __syncthreads();
        dote = lds_dote[0] + lds_dote[1] + lds_dote[2] + lds_dote[3]
             + lds_dote[4] + lds_dote[5] + lds_dote[6] + lds_dote[7];
    }

    // moment partial accumulators (this thread's 4 columns)
    float pa_m1[4] = {0, 0, 0, 0};   // sum x*s
    float pa_20[4] = {0, 0, 0, 0};   // sum x^2*s
    float pa_j1[4] = {0, 0, 0, 0};   // sum x^2*s*t_1
    float pa_j2[4] = {0, 0, 0, 0};
    float pa_j3[4] = {0, 0, 0, 0};
    float pa_nn[4] = {0, 0, 0, 0};   // sum x^2*s^2
    float pa_X1[4] = {0, 0, 0, 0};   // sum x       (LAY==0)
    float pa_X2[4] = {0, 0, 0, 0};   // sum x^2     (LAY==0)

    #pragma unroll
    for (int g = 0; g < RPB / 4; ++g) {
        float xr[4][4];
        float zp[4][4];
        #pragma unroll
        for (int rr = 0; rr < 4; ++rr) {
            const int row = row0 + g * 4 + rr;
            *(float4*)&xr[rr][0] = *(const float4*)(x + (size_t)row * DD + c0);
            zp[rr][0] = xr[rr][0] * u0[0] + xr[rr][1] * u0[1]
                      + xr[rr][2] * u0[2] + xr[rr][3] * u0[3];
            if constexpr (LAY >= 1)
                zp[rr][1] = xr[rr][0] * u1[0] + xr[rr][1] * u1[1]
                          + xr[rr][2] * u1[2] + xr[rr][3] * u1[3];
            if constexpr (LAY >= 2)
                zp[rr][2] = xr[rr][0] * u2[0] + xr[rr][1] * u2[1]
                          + xr[rr][2] * u2[2] + xr[rr][3] * u2[3];
            if constexpr (LAY >= 3)
                zp[rr][3] = xr[rr][0] * u3[0] + xr[rr][1] * u3[1]
                          + xr[rr][2] * u3[2] + xr[rr][3] * u3[3];
        }
        #pragma unroll
        for (int off = 32; off; off >>= 1) {
            #pragma unroll
            for (int rr = 0; rr < 4; ++rr) {
                zp[rr][0] += __shfl_xor(zp[rr][0], off, 64);
                if constexpr (LAY >= 1) zp[rr][1] += __shfl_xor(zp[rr][1], off, 64);
                if constexpr (LAY >= 2) zp[rr][2] += __shfl_xor(zp[rr][2], off, 64);
                if constexpr (LAY >= 3) zp[rr][3] += __shfl_xor(zp[rr][3], off, 64);
            }
        }
        if (lane == 0) {
            #pragma unroll
            for (int rr = 0; rr < 4; ++rr) {
                lds_z[wv][rr][0] = zp[rr][0];
                if constexpr (LAY >= 1) lds_z[wv][rr][1] = zp[rr][1];
                if constexpr (LAY >= 2) lds_z[wv][rr][2] = zp[rr][2];
                if constexpr (LAY >= 3) lds_z[wv][rr][3] = zp[rr][3];
            }
        }
        __syncthreads();
        if (t < 4) {
            const int row = row0 + g * 4 + t;
            float z[4] = {0, 0, 0, 0};
            #pragma unroll
            for (int w = 0; w < 8; ++w) {
                z[0] += lds_z[w][t][0];
                if constexpr (LAY >= 1) z[1] += lds_z[w][t][1];
                if constexpr (LAY >= 2) z[2] += lds_z[w][t][2];
                if constexpr (LAY >= 3) z[3] += lds_z[w][t][3];
            }
            float s = z[0] + dote;
            if constexpr (LAY >= 1) {
                const float tv = tbuf[0 * BB + row];
                lds_tv[t][0] = tv; s += tv * z[1];
            }
            if constexpr (LAY >= 2) {
                const float tv = tbuf[1 * BB + row];
                lds_tv[t][1] = tv; s += tv * z[2];
            }
            if constexpr (LAY >= 3) {
                const float tv = tbuf[2 * BB + row];
                lds_tv[t][2] = tv; s += tv * z[3];
            }
            tbuf[LAY * BB + row] = s;
            lds_s[t] = s;
        }
        __syncthreads();
        #pragma unroll
        for (int rr = 0; rr < 4; ++rr) {
            const float s = lds_s[rr];
            #pragma unroll
            for (int i = 0; i < 4; ++i) {
                const float xa = xr[rr][i];
                const float x2 = xa * xa;
                pa_m1[i] = fmaf(xa, s, pa_m1[i]);
                pa_20[i] = fmaf(x2, s, pa_20[i]);
                if constexpr (LAY >= 1) pa_j1[i] = fmaf(x2 * s, lds_tv[rr][0], pa_j1[i]);
                if constexpr (LAY >= 2) pa_j2[i] = fmaf(x2 * s, lds_tv[rr][1], pa_j2[i]);
                if constexpr (LAY >= 3) pa_j3[i] = fmaf(x2 * s, lds_tv[rr][2], pa_j3[i]);
                pa_nn[i] = fmaf(x2 * s, s, pa_nn[i]);
                if constexpr (LAY == 0) {
                    pa_X1[i] += xa;
                    pa_X2[i] += x2;
                }
            }
        }
    }

    // store partials: v ordering must match k_stats
    float* pp = partials + (size_t)blk * NV * DD + c0;
    *(float4*)(pp + 0 * DD) = *(float4*)&pa_m1[0];
    *(float4*)(pp + 1 * DD) = *(float4*)&pa_20[0];
    if constexpr (LAY == 0) {
        *(float4*)(pp + 2 * DD) = *(float4*)&pa_nn[0];
        *(float4*)(pp + 3 * DD) = *(float4*)&pa_X1[0];
        *(float4*)(pp + 4 * DD) = *(float4*)&pa_X2[0];
    } else {
        if constexpr (LAY >= 1) *(float4*)(pp + 2 * DD) = *(float4*)&pa_j1[0];
        if constexpr (LAY >= 2) *(float4*)(pp + 3 * DD) = *(float4*)&pa_j2[0];
        if constexpr (LAY >= 3) *(float4*)(pp + 4 * DD) = *(float4*)&pa_j3[0];
        *(float4*)(pp + (2 + LAY) * DD) = *(float4*)&pa_nn[0];
    }
}

// Stage A: partials[NB][nv*DD] -> mid[16][nv*DD]   (r13: single-stage reduce
// at 40 blocks was 42.7us latency-bound; this is the r10-proven wide shape)
__global__ __launch_bounds__(256) void k_red_a(
    const float* __restrict__ partials, float* __restrict__ mid,
    int nv, int nchunks)
{
    const int pg = blockIdx.x / nchunks;
    const int ec = blockIdx.x - pg * nchunks;
    const int e  = ec * 256 + threadIdx.x;        // e < nv*DD
    const int p0 = pg * (NB / 16);
    float acc = 0.f;
    #pragma unroll 4
    for (int p = 0; p < NB / 16; ++p)
        acc += partials[(size_t)(p0 + p) * nv * DD + e];
    mid[(size_t)pg * nv * DD + e] = acc;
}

// Stage B folded into stats: reduce 16 mids per moment, then the layer algebra.
template <int LAY>
__global__ __launch_bounds__(256) void k_stats(float* __restrict__ ws,
                                               const float* __restrict__ b4)
{
    constexpr int NV = (LAY == 0) ? 5 : (3 + LAY);
    const int d = blockIdx.x * 256 + threadIdx.x;
    constexpr int L = LAY + 1;
    float* M1 = ws + OFF_M1;
    float* M2 = ws + OFF_M2;
    const float* mid = ws + OFF_MID;
    float* a = ws + OFF_A;
    float* c = ws + OFF_C;
    float* e = ws + OFF_E;
    const float invB = 1.f / (float)BB;

    // finish the partial reduction: Mn[v] = sum over 16 groups
    float Mn[NV];
    #pragma unroll
    for (int v = 0; v < NV; ++v) {
        float acc = 0.f;
        #pragma unroll
        for (int pg = 0; pg < 16; ++pg)
            acc += mid[(size_t)pg * NV * DD + v * DD + d];
        Mn[v] = acc;
    }

    float g[5], m1v[5], m2v[5][5];

    g[0] = (LAY == 0) ? 1.f : a[d];
    #pragma unroll
    for (int k = 1; k <= LAY; ++k) g[k] = c[(k - 1) * DD + d];
    g[L] = 1.f;

    if constexpr (LAY == 0) m1v[0] = Mn[3];
    else                    m1v[0] = M1[0 * DD + d];
    #pragma unroll
    for (int k = 1; k <= LAY; ++k) m1v[k] = M1[k * DD + d];
    m1v[L] = Mn[0];

    if constexpr (LAY == 0) {
        m2v[0][0] = Mn[4];
    } else {
        #pragma unroll
        for (int k = 0; k <= LAY; ++k)
            #pragma unroll
            for (int j = 0; j <= LAY; ++j)
                if (j <= k) m2v[j][k] = M2[P2(j, k) * DD + d];
    }
    m2v[0][L] = Mn[1];
    #pragma unroll
    for (int j = 1; j <= LAY; ++j) m2v[j][L] = Mn[1 + j];
    m2v[L][L] = Mn[2 + LAY];

    // persist new moments
    M1[L * DD + d]         = m1v[L];
    M2[P2(0, L) * DD + d]  = m2v[0][L];
    #pragma unroll
    for (int j = 1; j <= LAY; ++j) M2[P2(j, L) * DD + d] = m2v[j][L];
    M2[P2(L, L) * DD + d]  = m2v[L][L];
    if constexpr (LAY == 0) { M1[0 * DD + d] = m1v[0]; M2[0 * DD + d] = m2v[0][0]; }

    // stats
    const float E = ((LAY == 0) ? 0.f : e[d]) + b4[LAY * DD + d];
    float mxG = 0.f;
    #pragma unroll
    for (int k = 0; k <= L; ++k) mxG += g[k] * m1v[k];
    mxG *= invB;
    const float mu = mxG + E;
    float ex2 = 0.f;
    #pragma unroll
    for (int k = 0; k <= L; ++k) {
        ex2 += g[k] * g[k] * m2v[k][k];
        #pragma unroll
        for (int j = 0; j <= L; ++j)
            if (j < k) ex2 += 2.f * g[j] * g[k] * m2v[j][k];
    }
    ex2 *= invB;
    const float second = ex2 + 2.f * E * mxG + E * E;
    const float var = fmaxf(second - mu * mu, 0.f);
    const float inv = rsqrtf(var + BN_EPS);

    a[d] = g[0] * inv;
    #pragma unroll
    for (int k = 1; k <= LAY; ++k) c[(k - 1) * DD + d] = g[k] * inv;
    c[(L - 1) * DD + d] = inv;
    e[d] = (E - mu) * inv;
}

// out[b,d] = x[b,d]*(a[d] + sum_k c_k[d]*t_k[b]) + e[d]
__global__ __launch_bounds__(256) void k_final(
    const float* __restrict__ x, const float* __restrict__ ws, float* __restrict__ out)
{
    const int t = threadIdx.x;
    const int blk = blockIdx.x;
    const int row0 = blk * 8;
    const int c0 = t * 8;
    const float* a = ws + OFF_A;
    const float* c = ws + OFF_C;
    const float* e = ws + OFF_E;
    const float* tbuf = ws + OFF_T;

    __shared__ float lt[4][8];
    if (t < 32) lt[t >> 3][t & 7] = tbuf[(t >> 3) * BB + row0 + (t & 7)];
    __syncthreads();

    float a8[8], e8[8], c8[4][8];
    *(float4*)&a8[0] = *(const float4*)(a + c0);
    *(float4*)&a8[4] = *(const float4*)(a + c0 + 4);
    *(float4*)&e8[0] = *(const float4*)(e + c0);
    *(float4*)&e8[4] = *(const float4*)(e + c0 + 4);
    #pragma unroll
    for (int k = 0; k < 4; ++k) {
        *(float4*)&c8[k][0] = *(const float4*)(c + k * DD + c0);
        *(float4*)&c8[k][4] = *(const float4*)(c + k * DD + c0 + 4);
    }
    #pragma unroll
    for (int r = 0; r < 8; ++r) {
        const size_t base = (size_t)(row0 + r) * DD + c0;
        float xv[8], o[8];
        *(float4*)&xv[0] = *(const float4*)(x + base);
        *(float4*)&xv[4] = *(const float4*)(x + base + 4);
        const float t0 = lt[0][r], t1 = lt[1][r], t2 = lt[2][r], t3 = lt[3][r];
        #pragma unroll
        for (int i = 0; i < 8; ++i) {
            float gg = a8[i];
            gg = fmaf(c8[0][i], t0, gg);
            gg = fmaf(c8[1][i], t1, gg);
            gg = fmaf(c8[2][i], t2, gg);
            gg = fmaf(c8[3][i], t3, gg);
            o[i] = fmaf(xv[i], gg, e8[i]);
        }
        *(float4*)(out + base)     = *(float4*)&o[0];
        *(float4*)(out + base + 4) = *(float4*)&o[4];
    }
}

extern "C" void kernel_launch(void* const* d_in, const int* in_sizes, int n_in,
                              void* d_out, int out_size, void* d_ws, size_t ws_size,
                              hipStream_t stream) {
    const float* x  = (const float*)d_in[0];   // [B, D]
    const float* w  = (const float*)d_in[1];   // [4, D]
    const float* bb = (const float*)d_in[2];   // [4, D]
    float* out = (float*)d_out;
    float* ws  = (float*)d_ws;
    float* partials = ws + OFF_P;
    float* mid      = ws + OFF_MID;

    k_pass<0><<<NB, PASS_THR, 0, stream>>>(x, w, ws);
    k_red_a<<<16 * 5 * 8, 256, 0, stream>>>(partials, mid, 5, 5 * 8);
    k_stats<0><<<8, 256, 0, stream>>>(ws, bb);

    k_pass<1><<<NB, PASS_THR, 0, stream>>>(x, w, ws);
    k_red_a<<<16 * 4 * 8, 256, 0, stream>>>(partials, mid, 4, 4 * 8);
    k_stats<1><<<8, 256, 0, stream>>>(ws, bb);

    k_pass<2><<<NB, PASS_THR, 0, stream>>>(x, w, ws);
    k_red_a<<<16 * 5 * 8, 256, 0, stream>>>(partials, mid, 5, 5 * 8);
    k_stats<2><<<8, 256, 0, stream>>>(ws, bb);

    k_pass<3><<<NB, PASS_THR, 0, stream>>>(x, w, ws);
    k_red_a<<<16 * 6 * 8, 256, 0, stream>>>(partials, mid, 6, 6 * 8);
    k_stats<3><<<8, 256, 0, stream>>>(ws, bb);

    k_final<<<BB / 8, 256, 0, stream>>>(x, ws, out);
}

// Round 16
// 134.445 us; speedup vs baseline: 2.5642x; 1.1458x over previous
//
#include <hip/hip_runtime.h>
#include <math.h>

#define BB 8192
#define DD 2048
#define BN_EPS 1e-5f
#define NB 512          // pass blocks
#define RPB 16          // rows per pass block
#define PASS_THR 512

// ws layout (floats)
#define OFF_T  0                    // tbuf[4][BB]   (t_k = s_{k-1})
#define OFF_A  (4 * BB)             // a[DD]
#define OFF_C  (OFF_A + DD)         // c[4][DD]
#define OFF_E  (OFF_C + 4 * DD)     // e[DD]
#define OFF_M1 (OFF_E + DD)         // M1[5][DD]   M1_k = sum_b x * t_k   (t_0 = 1)
#define OFF_M2 (OFF_M1 + 5 * DD)    // M2[15][DD]  M2_{jk} = sum_b x^2 t_j t_k, j<=k
#define OFF_MID (OFF_M2 + 15 * DD)  // mid[16][6][DD]  stage-A reduced partials
#define OFF_P  (OFF_MID + 16 * 6 * DD) // partials[NB][nv][DD]

__host__ __device__ constexpr int P2(int j, int k) { return k * (k + 1) / 2 + j; }

// One pass over x per layer. KEY change vs r15: s = z0 + sum_k t_k z_k and all
// t_k are already in tbuf BEFORE this pass -> fold the combination BEFORE the
// cross-lane reduce: per row butterfly ONE scalar, not (1+LAY). DS-pipe ops
// drop 4x at LAY=3 (the r15 hidden cost). Same FMA count, same partial
// layout/ordering as r15 (verified, absmax 0.125).
template <int LAY>
__global__ __launch_bounds__(PASS_THR) void k_pass(
    const float* __restrict__ x, const float* __restrict__ w4, float* __restrict__ ws)
{
    constexpr int NV = (LAY == 0) ? 5 : (3 + LAY);
    const float* avec = ws + OFF_A;
    const float* cvec = ws + OFF_C;
    const float* evec = ws + OFF_E;
    float* tbuf     = ws + OFF_T;
    float* partials = ws + OFF_P;

    const int t    = threadIdx.x;
    const int lane = t & 63;
    const int wv   = t >> 6;            // 8 waves
    const int blk  = blockIdx.x;
    const int row0 = blk * RPB;
    const int c0   = t * 4;
    const float* wl = w4 + LAY * DD;

    __shared__ float lds_z[8][8];       // [wave][rowInGroup] combined partial
    __shared__ float lds_s[8];
    __shared__ float lds_t[RPB][4];     // t_k per row, [row][k-1]
    __shared__ float lds_dote[8];

    float wr[4];
    *(float4*)&wr[0] = *(const float4*)(wl + c0);

    // u_j slices for this thread's 4 columns
    float u0[4], u1[4], u2[4], u3[4];
    if constexpr (LAY == 0) {
        #pragma unroll
        for (int i = 0; i < 4; ++i) u0[i] = wr[i];
    } else {
        float a4[4]; *(float4*)&a4[0] = *(const float4*)(avec + c0);
        #pragma unroll
        for (int i = 0; i < 4; ++i) u0[i] = a4[i] * wr[i];
    }
    if constexpr (LAY >= 1) {
        float cc[4]; *(float4*)&cc[0] = *(const float4*)(cvec + 0 * DD + c0);
        #pragma unroll
        for (int i = 0; i < 4; ++i) u1[i] = cc[i] * wr[i];
    }
    if constexpr (LAY >= 2) {
        float cc[4]; *(float4*)&cc[0] = *(const float4*)(cvec + 1 * DD + c0);
        #pragma unroll
        for (int i = 0; i < 4; ++i) u2[i] = cc[i] * wr[i];
    }
    if constexpr (LAY >= 3) {
        float cc[4]; *(float4*)&cc[0] = *(const float4*)(cvec + 2 * DD + c0);
        #pragma unroll
        for (int i = 0; i < 4; ++i) u3[i] = cc[i] * wr[i];
    }

    // cache this block's t values (written by earlier passes)
    if constexpr (LAY >= 1) {
        if (t < RPB) {
            lds_t[t][0] = tbuf[0 * BB + row0 + t];
            if constexpr (LAY >= 2) lds_t[t][1] = tbuf[1 * BB + row0 + t];
            if constexpr (LAY >= 3) lds_t[t][2] = tbuf[2 * BB + row0 + t];
        }
    }

    float dote = 0.f;
    if constexpr (LAY > 0) {
        float e4[4]; *(float4*)&e4[0] = *(const float4*)(evec + c0);
        float p = e4[0] * wr[0] + e4[1] * wr[1] + e4[2] * wr[2] + e4[3] * wr[3];
        #pragma unroll
        for (int off = 32; off; off >>= 1) p += __shfl_xor(p, off, 64);
        if (lane == 0) lds_dote[wv] = p;
        __syncthreads();   // also publishes lds_t
        dote = lds_dote[0] + lds_dote[1] + lds_dote[2] + lds_dote[3]
             + lds_dote[4] + lds_dote[5] + lds_dote[6] + lds_dote[7];
    }

    // moment partial accumulators (this thread's 4 columns)
    float pa_m1[4] = {0, 0, 0, 0};   // sum x*s
    float pa_20[4] = {0, 0, 0, 0};   // sum x^2*s
    float pa_j1[4] = {0, 0, 0, 0};   // sum x^2*s*t_1
    float pa_j2[4] = {0, 0, 0, 0};
    float pa_j3[4] = {0, 0, 0, 0};
    float pa_nn[4] = {0, 0, 0, 0};   // sum x^2*s^2
    float pa_X1[4] = {0, 0, 0, 0};   // sum x       (LAY==0)
    float pa_X2[4] = {0, 0, 0, 0};   // sum x^2     (LAY==0)

    #pragma unroll
    for (int g = 0; g < RPB / 8; ++g) {
        float xr[8][4];
        float cp[8];
        #pragma unroll
        for (int rr = 0; rr < 8; ++rr) {
            const int row = row0 + g * 8 + rr;
            *(float4*)&xr[rr][0] = *(const float4*)(x + (size_t)row * DD + c0);
            // combined weight per column: u0 + sum_k t_k u_k  (t's pre-known)
            float we[4];
            #pragma unroll
            for (int i = 0; i < 4; ++i) we[i] = u0[i];
            if constexpr (LAY >= 1) {
                const float t1 = lds_t[g * 8 + rr][0];
                #pragma unroll
                for (int i = 0; i < 4; ++i) we[i] = fmaf(t1, u1[i], we[i]);
            }
            if constexpr (LAY >= 2) {
                const float t2 = lds_t[g * 8 + rr][1];
                #pragma unroll
                for (int i = 0; i < 4; ++i) we[i] = fmaf(t2, u2[i], we[i]);
            }
            if constexpr (LAY >= 3) {
                const float t3 = lds_t[g * 8 + rr][2];
                #pragma unroll
                for (int i = 0; i < 4; ++i) we[i] = fmaf(t3, u3[i], we[i]);
            }
            float a = xr[rr][0] * we[0];
            a = fmaf(xr[rr][1], we[1], a);
            a = fmaf(xr[rr][2], we[2], a);
            a = fmaf(xr[rr][3], we[3], a);
            cp[rr] = a;
        }
        // ONE butterfly per row (was 1+LAY in r15)
        #pragma unroll
        for (int off = 32; off; off >>= 1) {
            #pragma unroll
            for (int rr = 0; rr < 8; ++rr)
                cp[rr] += __shfl_xor(cp[rr], off, 64);
        }
        if (lane == 0) {
            #pragma unroll
            for (int rr = 0; rr < 8; ++rr) lds_z[wv][rr] = cp[rr];
        }
        __syncthreads();
        if (t < 8) {
            const int row = row0 + g * 8 + t;
            float s = dote;
            #pragma unroll
            for (int w = 0; w < 8; ++w) s += lds_z[w][t];
            tbuf[LAY * BB + row] = s;
            lds_s[t] = s;
        }
        __syncthreads();
        #pragma unroll
        for (int rr = 0; rr < 8; ++rr) {
            const float s = lds_s[rr];
            #pragma unroll
            for (int i = 0; i < 4; ++i) {
                const float xa = xr[rr][i];
                const float x2 = xa * xa;
                const float xs2 = x2 * s;
                pa_m1[i] = fmaf(xa, s, pa_m1[i]);
                pa_20[i] += xs2;
                if constexpr (LAY >= 1) pa_j1[i] = fmaf(xs2, lds_t[g * 8 + rr][0], pa_j1[i]);
                if constexpr (LAY >= 2) pa_j2[i] = fmaf(xs2, lds_t[g * 8 + rr][1], pa_j2[i]);
                if constexpr (LAY >= 3) pa_j3[i] = fmaf(xs2, lds_t[g * 8 + rr][2], pa_j3[i]);
                pa_nn[i] = fmaf(xs2, s, pa_nn[i]);
                if constexpr (LAY == 0) {
                    pa_X1[i] += xa;
                    pa_X2[i] += x2;
                }
            }
        }
    }

    // store partials: v ordering must match k_stats (unchanged from r15)
    float* pp = partials + (size_t)blk * NV * DD + c0;
    *(float4*)(pp + 0 * DD) = *(float4*)&pa_m1[0];
    *(float4*)(pp + 1 * DD) = *(float4*)&pa_20[0];
    if constexpr (LAY == 0) {
        *(float4*)(pp + 2 * DD) = *(float4*)&pa_nn[0];
        *(float4*)(pp + 3 * DD) = *(float4*)&pa_X1[0];
        *(float4*)(pp + 4 * DD) = *(float4*)&pa_X2[0];
    } else {
        if constexpr (LAY >= 1) *(float4*)(pp + 2 * DD) = *(float4*)&pa_j1[0];
        if constexpr (LAY >= 2) *(float4*)(pp + 3 * DD) = *(float4*)&pa_j2[0];
        if constexpr (LAY >= 3) *(float4*)(pp + 4 * DD) = *(float4*)&pa_j3[0];
        *(float4*)(pp + (2 + LAY) * DD) = *(float4*)&pa_nn[0];
    }
}

// Stage A: partials[NB][nv*DD] -> mid[16][nv*DD]
__global__ __launch_bounds__(256) void k_red_a(
    const float* __restrict__ partials, float* __restrict__ mid,
    int nv, int nchunks)
{
    const int pg = blockIdx.x / nchunks;
    const int ec = blockIdx.x - pg * nchunks;
    const int e  = ec * 256 + threadIdx.x;        // e < nv*DD
    const int p0 = pg * (NB / 16);
    float acc = 0.f;
    #pragma unroll 4
    for (int p = 0; p < NB / 16; ++p)
        acc += partials[(size_t)(p0 + p) * nv * DD + e];
    mid[(size_t)pg * nv * DD + e] = acc;
}

// Stage B folded into stats: reduce 16 mids per moment, then the layer algebra.
template <int LAY>
__global__ __launch_bounds__(256) void k_stats(float* __restrict__ ws,
                                               const float* __restrict__ b4)
{
    constexpr int NV = (LAY == 0) ? 5 : (3 + LAY);
    const int d = blockIdx.x * 256 + threadIdx.x;
    constexpr int L = LAY + 1;
    float* M1 = ws + OFF_M1;
    float* M2 = ws + OFF_M2;
    const float* mid = ws + OFF_MID;
    float* a = ws + OFF_A;
    float* c = ws + OFF_C;
    float* e = ws + OFF_E;
    const float invB = 1.f / (float)BB;

    // finish the partial reduction: Mn[v] = sum over 16 groups
    float Mn[NV];
    #pragma unroll
    for (int v = 0; v < NV; ++v) {
        float acc = 0.f;
        #pragma unroll
        for (int pg = 0; pg < 16; ++pg)
            acc += mid[(size_t)pg * NV * DD + v * DD + d];
        Mn[v] = acc;
    }

    float g[5], m1v[5], m2v[5][5];

    g[0] = (LAY == 0) ? 1.f : a[d];
    #pragma unroll
    for (int k = 1; k <= LAY; ++k) g[k] = c[(k - 1) * DD + d];
    g[L] = 1.f;

    if constexpr (LAY == 0) m1v[0] = Mn[3];
    else                    m1v[0] = M1[0 * DD + d];
    #pragma unroll
    for (int k = 1; k <= LAY; ++k) m1v[k] = M1[k * DD + d];
    m1v[L] = Mn[0];

    if constexpr (LAY == 0) {
        m2v[0][0] = Mn[4];
    } else {
        #pragma unroll
        for (int k = 0; k <= LAY; ++k)
            #pragma unroll
            for (int j = 0; j <= LAY; ++j)
                if (j <= k) m2v[j][k] = M2[P2(j, k) * DD + d];
    }
    m2v[0][L] = Mn[1];
    #pragma unroll
    for (int j = 1; j <= LAY; ++j) m2v[j][L] = Mn[1 + j];
    m2v[L][L] = Mn[2 + LAY];

    // persist new moments
    M1[L * DD + d]         = m1v[L];
    M2[P2(0, L) * DD + d]  = m2v[0][L];
    #pragma unroll
    for (int j = 1; j <= LAY; ++j) M2[P2(j, L) * DD + d] = m2v[j][L];
    M2[P2(L, L) * DD + d]  = m2v[L][L];
    if constexpr (LAY == 0) { M1[0 * DD + d] = m1v[0]; M2[0 * DD + d] = m2v[0][0]; }

    // stats
    const float E = ((LAY == 0) ? 0.f : e[d]) + b4[LAY * DD + d];
    float mxG = 0.f;
    #pragma unroll
    for (int k = 0; k <= L; ++k) mxG += g[k] * m1v[k];
    mxG *= invB;
    const float mu = mxG + E;
    float ex2 = 0.f;
    #pragma unroll
    for (int k = 0; k <= L; ++k) {
        ex2 += g[k] * g[k] * m2v[k][k];
        #pragma unroll
        for (int j = 0; j <= L; ++j)
            if (j < k) ex2 += 2.f * g[j] * g[k] * m2v[j][k];
    }
    ex2 *= invB;
    const float second = ex2 + 2.f * E * mxG + E * E;
    const float var = fmaxf(second - mu * mu, 0.f);
    const float inv = rsqrtf(var + BN_EPS);

    a[d] = g[0] * inv;
    #pragma unroll
    for (int k = 1; k <= LAY; ++k) c[(k - 1) * DD + d] = g[k] * inv;
    c[(L - 1) * DD + d] = inv;
    e[d] = (E - mu) * inv;
}

// out[b,d] = x[b,d]*(a[d] + sum_k c_k[d]*t_k[b]) + e[d]
__global__ __launch_bounds__(256) void k_final(
    const float* __restrict__ x, const float* __restrict__ ws, float* __restrict__ out)
{
    const int t = threadIdx.x;
    const int blk = blockIdx.x;
    const int row0 = blk * 8;
    const int c0 = t * 8;
    const float* a = ws + OFF_A;
    const float* c = ws + OFF_C;
    const float* e = ws + OFF_E;
    const float* tbuf = ws + OFF_T;

    __shared__ float lt[4][8];
    if (t < 32) lt[t >> 3][t & 7] = tbuf[(t >> 3) * BB + row0 + (t & 7)];
    __syncthreads();

    float a8[8], e8[8], c8[4][8];
    *(float4*)&a8[0] = *(const float4*)(a + c0);
    *(float4*)&a8[4] = *(const float4*)(a + c0 + 4);
    *(float4*)&e8[0] = *(const float4*)(e + c0);
    *(float4*)&e8[4] = *(const float4*)(e + c0 + 4);
    #pragma unroll
    for (int k = 0; k < 4; ++k) {
        *(float4*)&c8[k][0] = *(const float4*)(c + k * DD + c0);
        *(float4*)&c8[k][4] = *(const float4*)(c + k * DD + c0 + 4);
    }
    #pragma unroll
    for (int r = 0; r < 8; ++r) {
        const size_t base = (size_t)(row0 + r) * DD + c0;
        float xv[8], o[8];
        *(float4*)&xv[0] = *(const float4*)(x + base);
        *(float4*)&xv[4] = *(const float4*)(x + base + 4);
        const float t0 = lt[0][r], t1 = lt[1][r], t2 = lt[2][r], t3 = lt[3][r];
        #pragma unroll
        for (int i = 0; i < 8; ++i) {
            float gg = a8[i];
            gg = fmaf(c8[0][i], t0, gg);
            gg = fmaf(c8[1][i], t1, gg);
            gg = fmaf(c8[2][i], t2, gg);
            gg = fmaf(c8[3][i], t3, gg);
            o[i] = fmaf(xv[i], gg, e8[i]);
        }
        *(float4*)(out + base)     = *(float4*)&o[0];
        *(float4*)(out + base + 4) = *(float4*)&o[4];
    }
}

extern "C" void kernel_launch(void* const* d_in, const int* in_sizes, int n_in,
                              void* d_out, int out_size, void* d_ws, size_t ws_size,
                              hipStream_t stream) {
    const float* x  = (const float*)d_in[0];   // [B, D]
    const float* w  = (const float*)d_in[1];   // [4, D]
    const float* bb = (const float*)d_in[2];   // [4, D]
    float* out = (float*)d_out;
    float* ws  = (float*)d_ws;
    float* partials = ws + OFF_P;
    float* mid      = ws + OFF_MID;

    k_pass<0><<<NB, PASS_THR, 0, stream>>>(x, w, ws);
    k_red_a<<<16 * 5 * 8, 256, 0, stream>>>(partials, mid, 5, 5 * 8);
    k_stats<0><<<8, 256, 0, stream>>>(ws, bb);

    k_pass<1><<<NB, PASS_THR, 0, stream>>>(x, w, ws);
    k_red_a<<<16 * 4 * 8, 256, 0, stream>>>(partials, mid, 4, 4 * 8);
    k_stats<1><<<8, 256, 0, stream>>>(ws, bb);

    k_pass<2><<<NB, PASS_THR, 0, stream>>>(x, w, ws);
    k_red_a<<<16 * 5 * 8, 256, 0, stream>>>(partials, mid, 5, 5 * 8);
    k_stats<2><<<8, 256, 0, stream>>>(ws, bb);

    k_pass<3><<<NB, PASS_THR, 0, stream>>>(x, w, ws);
    k_red_a<<<16 * 6 * 8, 256, 0, stream>>>(partials, mid, 6, 6 * 8);
    k_stats<3><<<8, 256, 0, stream>>>(ws, bb);

    k_final<<<BB / 8, 256, 0, stream>>>(x, ws, out);
}